// Round 1
// baseline (823.171 us; speedup 1.0000x reference)
//
#include <hip/hip_runtime.h>
#include <hip/hip_bf16.h>
#include <cstdint>

typedef __bf16 bf16;
typedef __bf16 bf16x8 __attribute__((ext_vector_type(8)));
typedef __bf16 bf16x4 __attribute__((ext_vector_type(4)));
typedef float  f32x4  __attribute__((ext_vector_type(4)));

constexpr int V_    = 32000;
constexpr int SMAX_ = 1024;
constexpr int D_    = 1024;
constexpr int H_    = 16;
constexpr int L_    = 2;
constexpr int DFF_  = 4096;
constexpr int WIN_  = 256;
constexpr int B_    = 2;
constexpr int M_    = B_ * SMAX_; // 2048

// ---------------------------------------------------------------------------
// Generic bf16 MFMA GEMM: C[M,N] = A[M,K] @ BT[N,K]^T  (both bf16, f32 accum)
// 128x128 tile, BK=32, 4 waves (2x2), 4x4 16x16x32 fragments per wave.
// Reg-staged LDS with row pad 40 elems (conflict-free fragment reads).
// EPI: 0 = bias->bf16, 1 = bias+gelu(exact)->bf16, 2 = bias+residual->f32
//      (in-place on resid), 3 = plain ->f32
// ---------------------------------------------------------------------------
template<int EPI>
__global__ __launch_bounds__(256) void gemm_bt(
    const bf16* __restrict__ A, const bf16* __restrict__ BT,
    const float* __restrict__ bias, float* __restrict__ resid,
    bf16* __restrict__ outb, float* __restrict__ outf,
    int Mm, int Nn, int Kk)
{
  constexpr int PAD = 40;
  __shared__ bf16 As[128 * PAD];
  __shared__ bf16 Bs[128 * PAD];
  const int t = threadIdx.x;
  const int lane = t & 63, w = t >> 6;
  const int wm = w >> 1, wn = w & 1;
  const long m0 = (long)blockIdx.y * 128, n0 = (long)blockIdx.x * 128;
  const int l16 = lane & 15, lh = lane >> 4;
  const int srow = t >> 2, sc = t & 3; // staging: 128 rows x 4 chunks of 16B

  f32x4 acc[4][4] = {};

  for (int k0 = 0; k0 < Kk; k0 += 32) {
    __syncthreads();
    {
      uint4 a0 = *(const uint4*)(A  + (m0 + srow     ) * Kk + k0 + sc * 8);
      uint4 a1 = *(const uint4*)(A  + (m0 + srow + 64) * Kk + k0 + sc * 8);
      uint4 b0 = *(const uint4*)(BT + (n0 + srow     ) * Kk + k0 + sc * 8);
      uint4 b1 = *(const uint4*)(BT + (n0 + srow + 64) * Kk + k0 + sc * 8);
      *(uint4*)(As + (srow     ) * PAD + sc * 8) = a0;
      *(uint4*)(As + (srow + 64) * PAD + sc * 8) = a1;
      *(uint4*)(Bs + (srow     ) * PAD + sc * 8) = b0;
      *(uint4*)(Bs + (srow + 64) * PAD + sc * 8) = b1;
    }
    __syncthreads();
    bf16x8 af[4], bf_[4];
    #pragma unroll
    for (int i = 0; i < 4; i++)
      af[i]  = *(const bf16x8*)(As + (wm * 64 + i * 16 + l16) * PAD + lh * 8);
    #pragma unroll
    for (int i = 0; i < 4; i++)
      bf_[i] = *(const bf16x8*)(Bs + (wn * 64 + i * 16 + l16) * PAD + lh * 8);
    #pragma unroll
    for (int mi = 0; mi < 4; mi++)
      #pragma unroll
      for (int ni = 0; ni < 4; ni++)
        acc[mi][ni] = __builtin_amdgcn_mfma_f32_16x16x32_bf16(af[mi], bf_[ni], acc[mi][ni], 0, 0, 0);
  }

  #pragma unroll
  for (int mi = 0; mi < 4; mi++) {
    #pragma unroll
    for (int ni = 0; ni < 4; ni++) {
      #pragma unroll
      for (int r = 0; r < 4; r++) {
        long row = m0 + wm * 64 + mi * 16 + lh * 4 + r;
        long col = n0 + wn * 64 + ni * 16 + l16;
        float v = acc[mi][ni][r];
        if (EPI == 0) {
          outb[row * Nn + col] = (bf16)(v + bias[col]);
        } else if (EPI == 1) {
          float xx = v + bias[col];
          outb[row * Nn + col] = (bf16)(0.5f * xx * (1.0f + erff(xx * 0.70710678118654752f)));
        } else if (EPI == 2) {
          resid[row * Nn + col] += v + bias[col];
        } else {
          outf[row * Nn + col] = v;
        }
      }
    }
  }
}

// ---------------------------------------------------------------------------
// Sliding-window causal flash attention.
// grid = B*H*(S/64); 4 waves, wave w owns 16 queries. 32-key tiles.
// qkv: [M, 3072] bf16 (q | k | v packed), head offset h*64.
// ---------------------------------------------------------------------------
__global__ __launch_bounds__(256) void attn_swa(
    const bf16* __restrict__ qkv, bf16* __restrict__ o)
{
  constexpr int PADK = 72;  // Q/K row pad (elems): rows 144B, 16B-aligned
  constexpr int PADV = 40;  // Vt / P row pad
  __shared__ bf16 Qs[64 * PADK];
  __shared__ bf16 Ks[32 * PADK];
  __shared__ bf16 Vt[64 * PADV];          // [hd][key] transposed
  __shared__ bf16 Ps[4][16 * PADV];       // per-wave P tile [16 q][32 keys]

  const int bid = blockIdx.x;
  const int qb = bid & 15;
  const int h  = (bid >> 4) & 15;
  const int b  = bid >> 8;
  const int q0 = qb * 64;
  const int t = threadIdx.x, lane = t & 63, w = t >> 6;
  const int l16 = lane & 15, lh = lane >> 4;

  // stage Q block [64][64]
  #pragma unroll
  for (int i = 0; i < 2; i++) {
    int e = t + i * 256;
    int row = e >> 3, cc = e & 7;
    uint4 g = *(const uint4*)(qkv + ((long)(b * SMAX_ + q0 + row)) * 3072 + h * 64 + cc * 8);
    *(uint4*)(Qs + row * PADK + cc * 8) = g;
  }
  __syncthreads();
  bf16x8 aq[2];
  const int qrow = w * 16 + l16;
  #pragma unroll
  for (int ks = 0; ks < 2; ks++)
    aq[ks] = *(const bf16x8*)(Qs + qrow * PADK + ks * 32 + lh * 8);

  float m_run[4], l_run[4];
  f32x4 oacc[4];
  #pragma unroll
  for (int r = 0; r < 4; r++) { m_run[r] = -1e30f; l_run[r] = 0.0f; }
  #pragma unroll
  for (int n = 0; n < 4; n++) oacc[n] = (f32x4){0.f, 0.f, 0.f, 0.f};

  const int tlo = q0 - (WIN_ - 1);
  const int jlo = (tlo <= 0) ? 0 : (tlo & ~31);
  const int iq  = q0 + w * 16 + lh * 4;   // query row for reg r is iq + r

  for (int j0 = jlo; j0 < q0 + 64; j0 += 32) {
    __syncthreads();
    { // stage K [32][64] and V transposed [64][32]
      int row = t >> 3, cc = t & 7;
      long base = ((long)(b * SMAX_ + j0 + row)) * 3072 + h * 64 + cc * 8;
      uint4 gk = *(const uint4*)(qkv + base + 1024);
      *(uint4*)(Ks + row * PADK + cc * 8) = gk;
      bf16x8 vv = *(const bf16x8*)(qkv + base + 2048);
      #pragma unroll
      for (int j = 0; j < 8; j++)
        Vt[(cc * 8 + j) * PADV + row] = vv[j];
    }
    __syncthreads();

    f32x4 s[2] = {(f32x4){0.f,0.f,0.f,0.f}, (f32x4){0.f,0.f,0.f,0.f}};
    #pragma unroll
    for (int nt = 0; nt < 2; nt++)
      #pragma unroll
      for (int ks = 0; ks < 2; ks++) {
        bf16x8 bk = *(const bf16x8*)(Ks + (nt * 16 + l16) * PADK + ks * 32 + lh * 8);
        s[nt] = __builtin_amdgcn_mfma_f32_16x16x32_bf16(aq[ks], bk, s[nt], 0, 0, 0);
      }

    float sc[2][4];
    #pragma unroll
    for (int nt = 0; nt < 2; nt++)
      #pragma unroll
      for (int r = 0; r < 4; r++) {
        int i = iq + r;
        int j = j0 + nt * 16 + l16;
        float v = s[nt][r] * 0.125f;
        bool ok = (j <= i) && (i - j < WIN_);
        sc[nt][r] = ok ? v : -1e30f;
      }

    float pb[2][4], alpha[4];
    #pragma unroll
    for (int r = 0; r < 4; r++) {
      float mt = fmaxf(sc[0][r], sc[1][r]);
      #pragma unroll
      for (int off = 1; off < 16; off <<= 1) mt = fmaxf(mt, __shfl_xor(mt, off, 64));
      float mn = fmaxf(m_run[r], mt);
      float a = __expf(m_run[r] - mn);
      m_run[r] = mn; alpha[r] = a;
      float p0 = __expf(sc[0][r] - mn);
      float p1 = __expf(sc[1][r] - mn);
      pb[0][r] = p0; pb[1][r] = p1;
      float ls = p0 + p1;
      #pragma unroll
      for (int off = 1; off < 16; off <<= 1) ls += __shfl_xor(ls, off, 64);
      l_run[r] = l_run[r] * a + ls;
    }
    #pragma unroll
    for (int n = 0; n < 4; n++)
      #pragma unroll
      for (int r = 0; r < 4; r++) oacc[n][r] *= alpha[r];

    #pragma unroll
    for (int r = 0; r < 4; r++) {
      int prow = lh * 4 + r;
      Ps[w][prow * PADV + l16]      = (bf16)pb[0][r];
      Ps[w][prow * PADV + 16 + l16] = (bf16)pb[1][r];
    }
    __syncthreads();

    bf16x8 pa = *(const bf16x8*)(&Ps[w][l16 * PADV + lh * 8]);
    #pragma unroll
    for (int n = 0; n < 4; n++) {
      bf16x8 bv = *(const bf16x8*)(Vt + (n * 16 + l16) * PADV + lh * 8);
      oacc[n] = __builtin_amdgcn_mfma_f32_16x16x32_bf16(pa, bv, oacc[n], 0, 0, 0);
    }
  }

  #pragma unroll
  for (int r = 0; r < 4; r++) {
    int i = iq + r;
    float inv = 1.0f / l_run[r];
    #pragma unroll
    for (int n = 0; n < 4; n++)
      o[((long)(b * SMAX_ + i)) * D_ + h * 64 + n * 16 + l16] = (bf16)(oacc[n][r] * inv);
  }
}

// ---------------------------------------------------------------------------
// f32 [K][N] -> bf16 [N][K] transpose+convert (32x32 tiles, block 32x8)
// ---------------------------------------------------------------------------
__global__ __launch_bounds__(256) void transpose_cvt(
    const float* __restrict__ src, bf16* __restrict__ dst,
    int Kk, int Nn, long srcL, long dstL)
{
  __shared__ float tile[32][33];
  const int tx = threadIdx.x, ty = threadIdx.y;
  const long n0 = (long)blockIdx.x * 32, k0 = (long)blockIdx.y * 32;
  src += (long)blockIdx.z * srcL;
  dst += (long)blockIdx.z * dstL;
  #pragma unroll
  for (int i = 0; i < 4; i++)
    tile[ty + i * 8][tx] = src[(k0 + ty + i * 8) * Nn + n0 + tx];
  __syncthreads();
  #pragma unroll
  for (int i = 0; i < 4; i++)
    dst[(n0 + ty + i * 8) * Kk + k0 + tx] = (bf16)tile[tx][ty + i * 8];
}

__global__ __launch_bounds__(256) void cvt_bf16(
    const float* __restrict__ src, bf16* __restrict__ dst, long n4)
{
  long i = (long)blockIdx.x * 256 + threadIdx.x;
  if (i >= n4) return;
  float4 v = ((const float4*)src)[i];
  bf16x4 o; o[0] = (bf16)v.x; o[1] = (bf16)v.y; o[2] = (bf16)v.z; o[3] = (bf16)v.w;
  ((bf16x4*)dst)[i] = o;
}

__global__ __launch_bounds__(256) void pack_bqkv(
    const float* __restrict__ bq, const float* __restrict__ bk,
    const float* __restrict__ bv, float* __restrict__ out)
{
  int i = blockIdx.x * 256 + threadIdx.x;
  if (i >= L_ * 3072) return;
  int l = i / 3072, c = i % 3072;
  float v = (c < 1024) ? bq[l * 1024 + c]
          : (c < 2048) ? bk[l * 1024 + c - 1024]
                       : bv[l * 1024 + c - 2048];
  out[i] = v;
}

__global__ __launch_bounds__(256) void embed_k(
    const int* __restrict__ ids, const float* __restrict__ emb,
    const float* __restrict__ pos, float* __restrict__ x)
{
  const int m = blockIdx.x, t = threadIdx.x;
  const int id = ids[m];
  const int s = m & (SMAX_ - 1);
  float4 e = ((const float4*)(emb + (long)id * D_))[t];
  float4 p = ((const float4*)(pos + (long)s * D_))[t];
  float4 r; r.x = e.x + p.x; r.y = e.y + p.y; r.z = e.z + p.z; r.w = e.w + p.w;
  ((float4*)(x + (long)m * D_))[t] = r;
}

__global__ __launch_bounds__(256) void rmsnorm_k(
    const float* __restrict__ x, const float* __restrict__ wgt,
    bf16* __restrict__ out)
{
  __shared__ float red[4];
  const int m = blockIdx.x, t = threadIdx.x;
  float4 v = ((const float4*)(x + (long)m * D_))[t];
  float ss = v.x * v.x + v.y * v.y + v.z * v.z + v.w * v.w;
  #pragma unroll
  for (int off = 1; off < 64; off <<= 1) ss += __shfl_xor(ss, off, 64);
  const int lane = t & 63, w = t >> 6;
  if (lane == 0) red[w] = ss;
  __syncthreads();
  float tot = red[0] + red[1] + red[2] + red[3];
  float rs = rsqrtf(tot * (1.0f / D_) + 1e-6f);
  float4 g = ((const float4*)wgt)[t];
  bf16x4 o;
  o[0] = (bf16)(v.x * rs * g.x); o[1] = (bf16)(v.y * rs * g.y);
  o[2] = (bf16)(v.z * rs * g.z); o[3] = (bf16)(v.w * rs * g.w);
  ((bf16x4*)(out + (long)m * D_))[t] = o;
}

// ---------------------------------------------------------------------------
extern "C" void kernel_launch(void* const* d_in, const int* in_sizes, int n_in,
                              void* d_out, int out_size, void* d_ws, size_t ws_size,
                              hipStream_t stream)
{
  const int*   ids = (const int*)d_in[0];
  const float* emb = (const float*)d_in[1];
  const float* pos = (const float*)d_in[2];
  const float* n1w = (const float*)d_in[3];
  const float* n2w = (const float*)d_in[4];
  const float* wq  = (const float*)d_in[5];
  const float* bq  = (const float*)d_in[6];
  const float* wk  = (const float*)d_in[7];
  const float* bk  = (const float*)d_in[8];
  const float* wv  = (const float*)d_in[9];
  const float* bv  = (const float*)d_in[10];
  const float* wo  = (const float*)d_in[11];
  const float* bo  = (const float*)d_in[12];
  const float* w1  = (const float*)d_in[13];
  const float* b1  = (const float*)d_in[14];
  const float* w2  = (const float*)d_in[15];
  const float* b2  = (const float*)d_in[16];
  const float* nfw = (const float*)d_in[17];

  char* p = (char*)d_ws;
  auto alloc = [&](size_t bytes) {
    char* r = p; p += (bytes + 255) & ~(size_t)255; return r;
  };
  bf16*  wqkv_t = (bf16*) alloc((size_t)L_ * 3 * 1024 * 1024 * 2);
  bf16*  wo_t   = (bf16*) alloc((size_t)L_ * 1024 * 1024 * 2);
  bf16*  w1_t   = (bf16*) alloc((size_t)L_ * 4096 * 1024 * 2);
  bf16*  w2_t   = (bf16*) alloc((size_t)L_ * 1024 * 4096 * 2);
  bf16*  emb_bf = (bf16*) alloc((size_t)V_ * D_ * 2);
  float* bqkv   = (float*)alloc((size_t)L_ * 3072 * 4);
  float* x      = (float*)alloc((size_t)M_ * D_ * 4);
  bf16*  hbuf   = (bf16*) alloc((size_t)M_ * D_ * 2);
  bf16*  qkv    = (bf16*) alloc((size_t)M_ * 3072 * 2);
  bf16*  obuf   = (bf16*) alloc((size_t)M_ * D_ * 2);
  bf16*  ff     = (bf16*) alloc((size_t)M_ * DFF_ * 2);

  const dim3 b32(32, 8, 1);
  transpose_cvt<<<dim3(32, 32, L_),  b32, 0, stream>>>(wq, wqkv_t,                1024, 1024, 1024 * 1024, 3 * 1024 * 1024);
  transpose_cvt<<<dim3(32, 32, L_),  b32, 0, stream>>>(wk, wqkv_t + 1024 * 1024,  1024, 1024, 1024 * 1024, 3 * 1024 * 1024);
  transpose_cvt<<<dim3(32, 32, L_),  b32, 0, stream>>>(wv, wqkv_t + 2*1024*1024,  1024, 1024, 1024 * 1024, 3 * 1024 * 1024);
  transpose_cvt<<<dim3(32, 32, L_),  b32, 0, stream>>>(wo, wo_t,                  1024, 1024, 1024 * 1024, 1024 * 1024);
  transpose_cvt<<<dim3(128, 32, L_), b32, 0, stream>>>(w1, w1_t,                  1024, 4096, 1024 * 4096, 4096 * 1024);
  transpose_cvt<<<dim3(32, 128, L_), b32, 0, stream>>>(w2, w2_t,                  4096, 1024, 4096 * 1024, 1024 * 4096);
  cvt_bf16<<<32000, 256, 0, stream>>>(emb, emb_bf, (long)V_ * D_ / 4);
  pack_bqkv<<<24, 256, 0, stream>>>(bq, bk, bv, bqkv);
  embed_k<<<M_, 256, 0, stream>>>(ids, emb, pos, x);

  for (int l = 0; l < L_; l++) {
    rmsnorm_k<<<M_, 256, 0, stream>>>(x, n1w + l * D_, hbuf);
    gemm_bt<0><<<dim3(3072 / 128, M_ / 128), 256, 0, stream>>>(
        hbuf, wqkv_t + (size_t)l * 3 * 1024 * 1024, bqkv + l * 3072,
        nullptr, qkv, nullptr, M_, 3072, 1024);
    attn_swa<<<B_ * H_ * (SMAX_ / 64), 256, 0, stream>>>(qkv, obuf);
    gemm_bt<2><<<dim3(1024 / 128, M_ / 128), 256, 0, stream>>>(
        obuf, wo_t + (size_t)l * 1024 * 1024, bo + l * D_,
        x, nullptr, nullptr, M_, 1024, 1024);
    rmsnorm_k<<<M_, 256, 0, stream>>>(x, n2w + l * D_, hbuf);
    gemm_bt<1><<<dim3(4096 / 128, M_ / 128), 256, 0, stream>>>(
        hbuf, w1_t + (size_t)l * 4096 * 1024, b1 + l * DFF_,
        nullptr, ff, nullptr, M_, 4096, 1024);
    gemm_bt<2><<<dim3(1024 / 128, M_ / 128), 256, 0, stream>>>(
        ff, w2_t + (size_t)l * 1024 * 4096, b2 + l * D_,
        x, nullptr, nullptr, M_, 1024, 4096);
  }
  rmsnorm_k<<<M_, 256, 0, stream>>>(x, nfw, hbuf);
  gemm_bt<3><<<dim3(V_ / 128, M_ / 128), 256, 0, stream>>>(
      hbuf, emb_bf, nullptr, nullptr, nullptr, (float*)d_out, M_, V_, 1024);
}

// Round 2
// 753.368 us; speedup vs baseline: 1.0927x; 1.0927x over previous
//
#include <hip/hip_runtime.h>
#include <hip/hip_bf16.h>
#include <cstdint>

typedef __bf16 bf16;
typedef __bf16 bf16x8 __attribute__((ext_vector_type(8)));
typedef __bf16 bf16x4 __attribute__((ext_vector_type(4)));
typedef float  f32x4  __attribute__((ext_vector_type(4)));

constexpr int V_    = 32000;
constexpr int SMAX_ = 1024;
constexpr int D_    = 1024;
constexpr int H_    = 16;
constexpr int L_    = 2;
constexpr int DFF_  = 4096;
constexpr int WIN_  = 256;
constexpr int B_    = 2;
constexpr int M_    = B_ * SMAX_; // 2048

// ---------------------------------------------------------------------------
// m97-structure bf16 MFMA GEMM: C[M,N] = A[M,K] @ BT[N,K]^T, f32 accum.
// BM x 128 tile, BK=32, 4 waves (2x2). Linear LDS + global_load_lds(16B).
// 1D grid with bijective XCD swizzle + M-fastest mapping (B-tile reuse in L2).
// EPI: 0 = bias->bf16, 1 = bias+gelu(exact)->bf16, 2 = bias+residual->f32
//      (in-place on resid), 3 = plain ->f32
// ---------------------------------------------------------------------------
template<int BM, int EPI>
__global__ __launch_bounds__(256) void gemm_bt(
    const bf16* __restrict__ A, const bf16* __restrict__ BT,
    const float* __restrict__ bias, float* __restrict__ resid,
    bf16* __restrict__ outb, float* __restrict__ outf,
    int Nn, int Kk, int nbyMask, int nbyShift)
{
  constexpr int WR = BM / 32;            // A fragments per wave
  __shared__ bf16 As[BM * 32];           // linear [row][32]
  __shared__ bf16 Bs[128 * 32];
  const int t = threadIdx.x, lane = t & 63, w = t >> 6;
  const int wm = w >> 1, wn = w & 1;
  const int l16 = lane & 15, lh = lane >> 4;
  const int lr = lane >> 2, lc = (lane & 3) * 8;   // staging lane -> row/col

  // bijective XCD swizzle (m204) + M-fastest tile order
  const int nwg = gridDim.x, bid = blockIdx.x;
  const int q = nwg >> 3, r = nwg & 7, xc = bid & 7, lcl = bid >> 3;
  const int wg = (xc < r ? xc * (q + 1) : r * (q + 1) + (xc - r) * q) + lcl;
  const long m0 = (long)(wg & nbyMask) * BM;
  const long n0 = (long)(wg >> nbyShift) * 128;

  f32x4 acc[WR][4] = {};

  for (int k0 = 0; k0 < Kk; k0 += 32) {
    __syncthreads();
    #pragma unroll
    for (int c = 0; c < BM / 64; ++c) {
      const int rb = (w * (BM / 64) + c) * 16;
      const bf16* g = A + (m0 + rb + lr) * (long)Kk + k0 + lc;
      __builtin_amdgcn_global_load_lds(
          (const __attribute__((address_space(1))) uint32_t*)g,
          (__attribute__((address_space(3))) uint32_t*)(As + rb * 32), 16, 0, 0);
    }
    #pragma unroll
    for (int c = 0; c < 2; ++c) {
      const int rb = (w * 2 + c) * 16;
      const bf16* g = BT + (n0 + rb + lr) * (long)Kk + k0 + lc;
      __builtin_amdgcn_global_load_lds(
          (const __attribute__((address_space(1))) uint32_t*)g,
          (__attribute__((address_space(3))) uint32_t*)(Bs + rb * 32), 16, 0, 0);
    }
    __syncthreads();

    bf16x8 af[WR], bfr[4];
    #pragma unroll
    for (int i = 0; i < WR; i++)
      af[i] = *(const bf16x8*)(As + (wm * (WR * 16) + i * 16 + l16) * 32 + lh * 8);
    #pragma unroll
    for (int i = 0; i < 4; i++)
      bfr[i] = *(const bf16x8*)(Bs + (wn * 64 + i * 16 + l16) * 32 + lh * 8);
    #pragma unroll
    for (int mi = 0; mi < WR; mi++)
      #pragma unroll
      for (int ni = 0; ni < 4; ni++)
        acc[mi][ni] = __builtin_amdgcn_mfma_f32_16x16x32_bf16(af[mi], bfr[ni], acc[mi][ni], 0, 0, 0);
  }

  #pragma unroll
  for (int mi = 0; mi < WR; mi++) {
    #pragma unroll
    for (int ni = 0; ni < 4; ni++) {
      #pragma unroll
      for (int rr = 0; rr < 4; rr++) {
        long row = m0 + wm * (WR * 16) + mi * 16 + lh * 4 + rr;
        long col = n0 + wn * 64 + ni * 16 + l16;
        float v = acc[mi][ni][rr];
        if (EPI == 0) {
          outb[row * Nn + col] = (bf16)(v + bias[col]);
        } else if (EPI == 1) {
          float xx = v + bias[col];
          outb[row * Nn + col] = (bf16)(0.5f * xx * (1.0f + erff(xx * 0.70710678118654752f)));
        } else if (EPI == 2) {
          resid[row * Nn + col] += v + bias[col];
        } else {
          outf[row * Nn + col] = v;
        }
      }
    }
  }
}

// ---------------------------------------------------------------------------
// Sliding-window causal flash attention (unchanged from round 1).
// ---------------------------------------------------------------------------
__global__ __launch_bounds__(256) void attn_swa(
    const bf16* __restrict__ qkv, bf16* __restrict__ o)
{
  constexpr int PADK = 72;
  constexpr int PADV = 40;
  __shared__ bf16 Qs[64 * PADK];
  __shared__ bf16 Ks[32 * PADK];
  __shared__ bf16 Vt[64 * PADV];
  __shared__ bf16 Ps[4][16 * PADV];

  const int bid = blockIdx.x;
  const int qb = bid & 15;
  const int h  = (bid >> 4) & 15;
  const int b  = bid >> 8;
  const int q0 = qb * 64;
  const int t = threadIdx.x, lane = t & 63, w = t >> 6;
  const int l16 = lane & 15, lh = lane >> 4;

  #pragma unroll
  for (int i = 0; i < 2; i++) {
    int e = t + i * 256;
    int row = e >> 3, cc = e & 7;
    uint4 g = *(const uint4*)(qkv + ((long)(b * SMAX_ + q0 + row)) * 3072 + h * 64 + cc * 8);
    *(uint4*)(Qs + row * PADK + cc * 8) = g;
  }
  __syncthreads();
  bf16x8 aq[2];
  const int qrow = w * 16 + l16;
  #pragma unroll
  for (int ks = 0; ks < 2; ks++)
    aq[ks] = *(const bf16x8*)(Qs + qrow * PADK + ks * 32 + lh * 8);

  float m_run[4], l_run[4];
  f32x4 oacc[4];
  #pragma unroll
  for (int rr = 0; rr < 4; rr++) { m_run[rr] = -1e30f; l_run[rr] = 0.0f; }
  #pragma unroll
  for (int n = 0; n < 4; n++) oacc[n] = (f32x4){0.f, 0.f, 0.f, 0.f};

  const int tlo = q0 - (WIN_ - 1);
  const int jlo = (tlo <= 0) ? 0 : (tlo & ~31);
  const int iq  = q0 + w * 16 + lh * 4;

  for (int j0 = jlo; j0 < q0 + 64; j0 += 32) {
    __syncthreads();
    {
      int row = t >> 3, cc = t & 7;
      long base = ((long)(b * SMAX_ + j0 + row)) * 3072 + h * 64 + cc * 8;
      uint4 gk = *(const uint4*)(qkv + base + 1024);
      *(uint4*)(Ks + row * PADK + cc * 8) = gk;
      bf16x8 vv = *(const bf16x8*)(qkv + base + 2048);
      #pragma unroll
      for (int j = 0; j < 8; j++)
        Vt[(cc * 8 + j) * PADV + row] = vv[j];
    }
    __syncthreads();

    f32x4 s[2] = {(f32x4){0.f,0.f,0.f,0.f}, (f32x4){0.f,0.f,0.f,0.f}};
    #pragma unroll
    for (int nt = 0; nt < 2; nt++)
      #pragma unroll
      for (int ks = 0; ks < 2; ks++) {
        bf16x8 bk = *(const bf16x8*)(Ks + (nt * 16 + l16) * PADK + ks * 32 + lh * 8);
        s[nt] = __builtin_amdgcn_mfma_f32_16x16x32_bf16(aq[ks], bk, s[nt], 0, 0, 0);
      }

    float sc[2][4];
    #pragma unroll
    for (int nt = 0; nt < 2; nt++)
      #pragma unroll
      for (int rr = 0; rr < 4; rr++) {
        int i = iq + rr;
        int j = j0 + nt * 16 + l16;
        float v = s[nt][rr] * 0.125f;
        bool ok = (j <= i) && (i - j < WIN_);
        sc[nt][rr] = ok ? v : -1e30f;
      }

    float pb[2][4], alpha[4];
    #pragma unroll
    for (int rr = 0; rr < 4; rr++) {
      float mt = fmaxf(sc[0][rr], sc[1][rr]);
      #pragma unroll
      for (int off = 1; off < 16; off <<= 1) mt = fmaxf(mt, __shfl_xor(mt, off, 64));
      float mn = fmaxf(m_run[rr], mt);
      float a = __expf(m_run[rr] - mn);
      m_run[rr] = mn; alpha[rr] = a;
      float p0 = __expf(sc[0][rr] - mn);
      float p1 = __expf(sc[1][rr] - mn);
      pb[0][rr] = p0; pb[1][rr] = p1;
      float ls = p0 + p1;
      #pragma unroll
      for (int off = 1; off < 16; off <<= 1) ls += __shfl_xor(ls, off, 64);
      l_run[rr] = l_run[rr] * a + ls;
    }
    #pragma unroll
    for (int n = 0; n < 4; n++)
      #pragma unroll
      for (int rr = 0; rr < 4; rr++) oacc[n][rr] *= alpha[rr];

    #pragma unroll
    for (int rr = 0; rr < 4; rr++) {
      int prow = lh * 4 + rr;
      Ps[w][prow * PADV + l16]      = (bf16)pb[0][rr];
      Ps[w][prow * PADV + 16 + l16] = (bf16)pb[1][rr];
    }
    __syncthreads();

    bf16x8 pa = *(const bf16x8*)(&Ps[w][l16 * PADV + lh * 8]);
    #pragma unroll
    for (int n = 0; n < 4; n++) {
      bf16x8 bv = *(const bf16x8*)(Vt + (n * 16 + l16) * PADV + lh * 8);
      oacc[n] = __builtin_amdgcn_mfma_f32_16x16x32_bf16(pa, bv, oacc[n], 0, 0, 0);
    }
  }

  #pragma unroll
  for (int rr = 0; rr < 4; rr++) {
    int i = iq + rr;
    float inv = 1.0f / l_run[rr];
    #pragma unroll
    for (int n = 0; n < 4; n++)
      o[((long)(b * SMAX_ + i)) * D_ + h * 64 + n * 16 + l16] = (bf16)(oacc[n][rr] * inv);
  }
}

// ---------------------------------------------------------------------------
__global__ __launch_bounds__(256) void transpose_cvt(
    const float* __restrict__ src, bf16* __restrict__ dst,
    int Kk, int Nn, long srcL, long dstL)
{
  __shared__ float tile[32][33];
  const int tx = threadIdx.x, ty = threadIdx.y;
  const long n0 = (long)blockIdx.x * 32, k0 = (long)blockIdx.y * 32;
  src += (long)blockIdx.z * srcL;
  dst += (long)blockIdx.z * dstL;
  #pragma unroll
  for (int i = 0; i < 4; i++)
    tile[ty + i * 8][tx] = src[(k0 + ty + i * 8) * Nn + n0 + tx];
  __syncthreads();
  #pragma unroll
  for (int i = 0; i < 4; i++)
    dst[(n0 + ty + i * 8) * Kk + k0 + tx] = (bf16)tile[tx][ty + i * 8];
}

__global__ __launch_bounds__(256) void cvt_bf16(
    const float* __restrict__ src, bf16* __restrict__ dst, long n4)
{
  long i = (long)blockIdx.x * 256 + threadIdx.x;
  if (i >= n4) return;
  float4 v = ((const float4*)src)[i];
  bf16x4 o; o[0] = (bf16)v.x; o[1] = (bf16)v.y; o[2] = (bf16)v.z; o[3] = (bf16)v.w;
  ((bf16x4*)dst)[i] = o;
}

__global__ __launch_bounds__(256) void pack_bqkv(
    const float* __restrict__ bq, const float* __restrict__ bk,
    const float* __restrict__ bv, float* __restrict__ out)
{
  int i = blockIdx.x * 256 + threadIdx.x;
  if (i >= L_ * 3072) return;
  int l = i / 3072, c = i % 3072;
  float v = (c < 1024) ? bq[l * 1024 + c]
          : (c < 2048) ? bk[l * 1024 + c - 1024]
                       : bv[l * 1024 + c - 2048];
  out[i] = v;
}

__global__ __launch_bounds__(256) void embed_k(
    const int* __restrict__ ids, const float* __restrict__ emb,
    const float* __restrict__ pos, float* __restrict__ x)
{
  const int m = blockIdx.x, t = threadIdx.x;
  const int id = ids[m];
  const int s = m & (SMAX_ - 1);
  float4 e = ((const float4*)(emb + (long)id * D_))[t];
  float4 p = ((const float4*)(pos + (long)s * D_))[t];
  float4 rr; rr.x = e.x + p.x; rr.y = e.y + p.y; rr.z = e.z + p.z; rr.w = e.w + p.w;
  ((float4*)(x + (long)m * D_))[t] = rr;
}

__global__ __launch_bounds__(256) void rmsnorm_k(
    const float* __restrict__ x, const float* __restrict__ wgt,
    bf16* __restrict__ out)
{
  __shared__ float red[4];
  const int m = blockIdx.x, t = threadIdx.x;
  float4 v = ((const float4*)(x + (long)m * D_))[t];
  float ss = v.x * v.x + v.y * v.y + v.z * v.z + v.w * v.w;
  #pragma unroll
  for (int off = 1; off < 64; off <<= 1) ss += __shfl_xor(ss, off, 64);
  const int lane = t & 63, w = t >> 6;
  if (lane == 0) red[w] = ss;
  __syncthreads();
  float tot = red[0] + red[1] + red[2] + red[3];
  float rs = rsqrtf(tot * (1.0f / D_) + 1e-6f);
  float4 g = ((const float4*)wgt)[t];
  bf16x4 o;
  o[0] = (bf16)(v.x * rs * g.x); o[1] = (bf16)(v.y * rs * g.y);
  o[2] = (bf16)(v.z * rs * g.z); o[3] = (bf16)(v.w * rs * g.w);
  ((bf16x4*)(out + (long)m * D_))[t] = o;
}

// ---------------------------------------------------------------------------
extern "C" void kernel_launch(void* const* d_in, const int* in_sizes, int n_in,
                              void* d_out, int out_size, void* d_ws, size_t ws_size,
                              hipStream_t stream)
{
  const int*   ids = (const int*)d_in[0];
  const float* emb = (const float*)d_in[1];
  const float* pos = (const float*)d_in[2];
  const float* n1w = (const float*)d_in[3];
  const float* n2w = (const float*)d_in[4];
  const float* wq  = (const float*)d_in[5];
  const float* bq  = (const float*)d_in[6];
  const float* wk  = (const float*)d_in[7];
  const float* bk  = (const float*)d_in[8];
  const float* wv  = (const float*)d_in[9];
  const float* bv  = (const float*)d_in[10];
  const float* wo  = (const float*)d_in[11];
  const float* bo  = (const float*)d_in[12];
  const float* w1  = (const float*)d_in[13];
  const float* b1  = (const float*)d_in[14];
  const float* w2  = (const float*)d_in[15];
  const float* b2  = (const float*)d_in[16];
  const float* nfw = (const float*)d_in[17];

  char* p = (char*)d_ws;
  auto alloc = [&](size_t bytes) {
    char* rr = p; p += (bytes + 255) & ~(size_t)255; return rr;
  };
  bf16*  wqkv_t = (bf16*) alloc((size_t)L_ * 3 * 1024 * 1024 * 2);
  bf16*  wo_t   = (bf16*) alloc((size_t)L_ * 1024 * 1024 * 2);
  bf16*  w1_t   = (bf16*) alloc((size_t)L_ * 4096 * 1024 * 2);
  bf16*  w2_t   = (bf16*) alloc((size_t)L_ * 1024 * 4096 * 2);
  bf16*  emb_bf = (bf16*) alloc((size_t)V_ * D_ * 2);
  float* bqkv   = (float*)alloc((size_t)L_ * 3072 * 4);
  float* x      = (float*)alloc((size_t)M_ * D_ * 4);
  bf16*  hbuf   = (bf16*) alloc((size_t)M_ * D_ * 2);
  bf16*  qkv    = (bf16*) alloc((size_t)M_ * 3072 * 2);
  bf16*  obuf   = (bf16*) alloc((size_t)M_ * D_ * 2);
  bf16*  ff     = (bf16*) alloc((size_t)M_ * DFF_ * 2);

  const dim3 b32(32, 8, 1);
  transpose_cvt<<<dim3(32, 32, L_),  b32, 0, stream>>>(wq, wqkv_t,                1024, 1024, 1024 * 1024, 3 * 1024 * 1024);
  transpose_cvt<<<dim3(32, 32, L_),  b32, 0, stream>>>(wk, wqkv_t + 1024 * 1024,  1024, 1024, 1024 * 1024, 3 * 1024 * 1024);
  transpose_cvt<<<dim3(32, 32, L_),  b32, 0, stream>>>(wv, wqkv_t + 2*1024*1024,  1024, 1024, 1024 * 1024, 3 * 1024 * 1024);
  transpose_cvt<<<dim3(32, 32, L_),  b32, 0, stream>>>(wo, wo_t,                  1024, 1024, 1024 * 1024, 1024 * 1024);
  transpose_cvt<<<dim3(128, 32, L_), b32, 0, stream>>>(w1, w1_t,                  1024, 4096, 1024 * 4096, 4096 * 1024);
  transpose_cvt<<<dim3(32, 128, L_), b32, 0, stream>>>(w2, w2_t,                  4096, 1024, 4096 * 1024, 1024 * 4096);
  cvt_bf16<<<32000, 256, 0, stream>>>(emb, emb_bf, (long)V_ * D_ / 4);
  pack_bqkv<<<24, 256, 0, stream>>>(bq, bk, bv, bqkv);
  embed_k<<<M_, 256, 0, stream>>>(ids, emb, pos, x);

  for (int l = 0; l < L_; l++) {
    rmsnorm_k<<<M_, 256, 0, stream>>>(x, n1w + l * D_, hbuf);
    gemm_bt<128, 0><<<dim3(16 * 24), 256, 0, stream>>>(
        hbuf, wqkv_t + (size_t)l * 3 * 1024 * 1024, bqkv + l * 3072,
        nullptr, qkv, nullptr, 3072, 1024, 15, 4);
    attn_swa<<<B_ * H_ * (SMAX_ / 64), 256, 0, stream>>>(qkv, obuf);
    gemm_bt<64, 2><<<dim3(32 * 8), 256, 0, stream>>>(
        obuf, wo_t + (size_t)l * 1024 * 1024, bo + l * D_,
        x, nullptr, nullptr, 1024, 1024, 31, 5);
    rmsnorm_k<<<M_, 256, 0, stream>>>(x, n2w + l * D_, hbuf);
    gemm_bt<128, 1><<<dim3(16 * 32), 256, 0, stream>>>(
        hbuf, w1_t + (size_t)l * 4096 * 1024, b1 + l * DFF_,
        nullptr, ff, nullptr, 4096, 1024, 15, 4);
    gemm_bt<64, 2><<<dim3(32 * 8), 256, 0, stream>>>(
        ff, w2_t + (size_t)l * 1024 * 4096, b2 + l * D_,
        x, nullptr, nullptr, 1024, 4096, 31, 5);
  }
  rmsnorm_k<<<M_, 256, 0, stream>>>(x, nfw, hbuf);
  gemm_bt<128, 3><<<dim3(16 * 250), 256, 0, stream>>>(
      hbuf, emb_bf, nullptr, nullptr, nullptr, (float*)d_out, 32000, 1024, 15, 4);
}

// Round 3
// 722.940 us; speedup vs baseline: 1.1386x; 1.0421x over previous
//
#include <hip/hip_runtime.h>
#include <hip/hip_bf16.h>
#include <cstdint>

typedef __bf16 bf16;
typedef __bf16 bf16x8 __attribute__((ext_vector_type(8)));
typedef __bf16 bf16x4 __attribute__((ext_vector_type(4)));
typedef float  f32x4  __attribute__((ext_vector_type(4)));

constexpr int V_    = 32000;
constexpr int SMAX_ = 1024;
constexpr int D_    = 1024;
constexpr int H_    = 16;
constexpr int L_    = 2;
constexpr int DFF_  = 4096;
constexpr int WIN_  = 256;
constexpr int B_    = 2;
constexpr int M_    = B_ * SMAX_; // 2048

#define BAR_()   { __builtin_amdgcn_s_barrier(); __builtin_amdgcn_sched_barrier(0); }
#define LGKM0_() { asm volatile("s_waitcnt lgkmcnt(0)" ::: "memory"); __builtin_amdgcn_sched_barrier(0); }
#define VM4_()   { asm volatile("s_waitcnt vmcnt(4)" ::: "memory"); __builtin_amdgcn_sched_barrier(0); }

// ---------------------------------------------------------------------------
// 256x256 8-phase GEMM for the LM head: out[M,N] = A[M,1024] @ BT[N,1024]^T,
// f32 out. 512 thr (8 waves 2Mx4N), BK=64 as two K=32 halves, double-buffered
// LDS by K-step parity, counted vmcnt(4), st-swizzled LDS, setprio MFMA.
// Grid = 8*(N/256), bijective XCD chunking, M-fastest within XCD.
// ---------------------------------------------------------------------------
__global__ __launch_bounds__(512, 1) void gemm256_lm(
    const bf16* __restrict__ A, const bf16* __restrict__ BT,
    float* __restrict__ outf, int Nn)
{
  constexpr int KK = 1024, KT = KK / 64;
  __shared__ __align__(16) bf16 lds[65536];   // A0,A1,B0,B1 x 16384 elems (32KB)

  const int t = threadIdx.x, lane = t & 63, w = t >> 6;
  const int l16 = lane & 15, lh = lane >> 4;
  const int wm = w >> 2, wn = w & 3;

  // XCD chunking: nwg = 8*(Nn/256) (multiple of 8). wg = n*8 + m.
  const int nloc = gridDim.x >> 3;
  const int wg = (blockIdx.x & 7) * nloc + (blockIdx.x >> 3);
  const long m0 = (long)(wg & 7) * 256;
  const long n0 = (long)(wg >> 3) * 256;

  auto STAGE = [&](const bf16* gsrc, long rowBase, bf16* dstBase, int ks, int j, int kk0) {
    int o  = ks * 16384 + j * 8192 + (w << 10) + (lane << 4);  // phys byte in 32KB buf
    int lB = o ^ (((o >> 6) & 3) << 4);
    int row = (lB & 16383) >> 6;
    int ce  = (lB & 63) >> 1;
    const bf16* g = gsrc + (rowBase + row) * (long)KK + kk0 + ks * 32 + ce;
    __builtin_amdgcn_global_load_lds(
        (const __attribute__((address_space(1))) uint32_t*)g,
        (__attribute__((address_space(3))) uint32_t*)(dstBase + ks * 8192 + j * 4096 + (w << 9)),
        16, 0, 0);
  };
  auto LDF = [&](const bf16* base, int ks, int row) -> bf16x8 {
    int off = ks * 8192 + row * 32 + ((lh * 8) ^ ((l16 & 3) << 3));
    return *(const bf16x8*)(base + off);
  };

  f32x4 acc[8][4] = {};

  // prologue: stage tile 0 into buf 0, same issue order as loop phases
  {
    bf16* A0 = lds; bf16* B0 = lds + 32768;
    STAGE(A, m0, A0, 0, 0, 0); STAGE(A, m0, A0, 0, 1, 0);
    STAGE(BT, n0, B0, 0, 0, 0); STAGE(BT, n0, B0, 0, 1, 0);
    STAGE(A, m0, A0, 1, 0, 0); STAGE(A, m0, A0, 1, 1, 0);
    STAGE(BT, n0, B0, 1, 0, 0); STAGE(BT, n0, B0, 1, 1, 0);
  }
  VM4_(); BAR_();

  for (int tt = 0; tt < KT; ++tt) {
    const int c = tt & 1;
    const bf16* As = lds + c * 16384;
    const bf16* Bs = lds + 32768 + c * 16384;
    bf16* Asn = lds + (c ^ 1) * 16384;
    bf16* Bsn = lds + 32768 + (c ^ 1) * 16384;
    const int k1 = ((tt + 1) % KT) * 64;   // last iter redundantly re-stages tile 0

    bf16x8 af[8], bb0, bb1;
    #pragma unroll
    for (int ks = 0; ks < 2; ++ks) {
      // ---- phase A: ni 0,1 ----
      #pragma unroll
      for (int mi = 0; mi < 8; ++mi) af[mi] = LDF(As, ks, wm * 128 + mi * 16 + l16);
      bb0 = LDF(Bs, ks, wn * 64 + 0  + l16);
      bb1 = LDF(Bs, ks, wn * 64 + 16 + l16);
      STAGE(A, m0, Asn, ks, 0, k1); STAGE(A, m0, Asn, ks, 1, k1);
      BAR_(); LGKM0_();
      __builtin_amdgcn_s_setprio(1);
      #pragma unroll
      for (int mi = 0; mi < 8; ++mi) {
        acc[mi][0] = __builtin_amdgcn_mfma_f32_16x16x32_bf16(af[mi], bb0, acc[mi][0], 0, 0, 0);
        acc[mi][1] = __builtin_amdgcn_mfma_f32_16x16x32_bf16(af[mi], bb1, acc[mi][1], 0, 0, 0);
      }
      __builtin_amdgcn_s_setprio(0);
      BAR_();
      // ---- phase B: ni 2,3 ----
      bb0 = LDF(Bs, ks, wn * 64 + 32 + l16);
      bb1 = LDF(Bs, ks, wn * 64 + 48 + l16);
      STAGE(BT, n0, Bsn, ks, 0, k1); STAGE(BT, n0, Bsn, ks, 1, k1);
      BAR_(); LGKM0_();
      __builtin_amdgcn_s_setprio(1);
      #pragma unroll
      for (int mi = 0; mi < 8; ++mi) {
        acc[mi][2] = __builtin_amdgcn_mfma_f32_16x16x32_bf16(af[mi], bb0, acc[mi][2], 0, 0, 0);
        acc[mi][3] = __builtin_amdgcn_mfma_f32_16x16x32_bf16(af[mi], bb1, acc[mi][3], 0, 0, 0);
      }
      __builtin_amdgcn_s_setprio(0);
      VM4_(); BAR_();
    }
  }

  #pragma unroll
  for (int mi = 0; mi < 8; ++mi)
    #pragma unroll
    for (int ni = 0; ni < 4; ++ni)
      #pragma unroll
      for (int rr = 0; rr < 4; ++rr) {
        long row = m0 + wm * 128 + mi * 16 + lh * 4 + rr;
        long col = n0 + wn * 64 + ni * 16 + l16;
        outf[row * Nn + col] = acc[mi][ni][rr];
      }
}

// ---------------------------------------------------------------------------
// m97-structure bf16 MFMA GEMM (round-2, unchanged): C = A @ BT^T.
// ---------------------------------------------------------------------------
template<int BM, int EPI>
__global__ __launch_bounds__(256) void gemm_bt(
    const bf16* __restrict__ A, const bf16* __restrict__ BT,
    const float* __restrict__ bias, float* __restrict__ resid,
    bf16* __restrict__ outb, float* __restrict__ outf,
    int Nn, int Kk, int nbyMask, int nbyShift)
{
  constexpr int WR = BM / 32;
  __shared__ bf16 As[BM * 32];
  __shared__ bf16 Bs[128 * 32];
  const int t = threadIdx.x, lane = t & 63, w = t >> 6;
  const int wm = w >> 1, wn = w & 1;
  const int l16 = lane & 15, lh = lane >> 4;
  const int lr = lane >> 2, lc = (lane & 3) * 8;

  const int nwg = gridDim.x, bid = blockIdx.x;
  const int q = nwg >> 3, r = nwg & 7, xc = bid & 7, lcl = bid >> 3;
  const int wg = (xc < r ? xc * (q + 1) : r * (q + 1) + (xc - r) * q) + lcl;
  const long m0 = (long)(wg & nbyMask) * BM;
  const long n0 = (long)(wg >> nbyShift) * 128;

  f32x4 acc[WR][4] = {};

  for (int k0 = 0; k0 < Kk; k0 += 32) {
    __syncthreads();
    #pragma unroll
    for (int c = 0; c < BM / 64; ++c) {
      const int rb = (w * (BM / 64) + c) * 16;
      const bf16* g = A + (m0 + rb + lr) * (long)Kk + k0 + lc;
      __builtin_amdgcn_global_load_lds(
          (const __attribute__((address_space(1))) uint32_t*)g,
          (__attribute__((address_space(3))) uint32_t*)(As + rb * 32), 16, 0, 0);
    }
    #pragma unroll
    for (int c = 0; c < 2; ++c) {
      const int rb = (w * 2 + c) * 16;
      const bf16* g = BT + (n0 + rb + lr) * (long)Kk + k0 + lc;
      __builtin_amdgcn_global_load_lds(
          (const __attribute__((address_space(1))) uint32_t*)g,
          (__attribute__((address_space(3))) uint32_t*)(Bs + rb * 32), 16, 0, 0);
    }
    __syncthreads();

    bf16x8 af[WR], bfr[4];
    #pragma unroll
    for (int i = 0; i < WR; i++)
      af[i] = *(const bf16x8*)(As + (wm * (WR * 16) + i * 16 + l16) * 32 + lh * 8);
    #pragma unroll
    for (int i = 0; i < 4; i++)
      bfr[i] = *(const bf16x8*)(Bs + (wn * 64 + i * 16 + l16) * 32 + lh * 8);
    #pragma unroll
    for (int mi = 0; mi < WR; mi++)
      #pragma unroll
      for (int ni = 0; ni < 4; ni++)
        acc[mi][ni] = __builtin_amdgcn_mfma_f32_16x16x32_bf16(af[mi], bfr[ni], acc[mi][ni], 0, 0, 0);
  }

  #pragma unroll
  for (int mi = 0; mi < WR; mi++) {
    #pragma unroll
    for (int ni = 0; ni < 4; ni++) {
      #pragma unroll
      for (int rr = 0; rr < 4; rr++) {
        long row = m0 + wm * (WR * 16) + mi * 16 + lh * 4 + rr;
        long col = n0 + wn * 64 + ni * 16 + l16;
        float v = acc[mi][ni][rr];
        if (EPI == 0) {
          outb[row * Nn + col] = (bf16)(v + bias[col]);
        } else if (EPI == 1) {
          float xx = v + bias[col];
          outb[row * Nn + col] = (bf16)(0.5f * xx * (1.0f + erff(xx * 0.70710678118654752f)));
        } else if (EPI == 2) {
          resid[row * Nn + col] += v + bias[col];
        } else {
          outf[row * Nn + col] = v;
        }
      }
    }
  }
}

// ---------------------------------------------------------------------------
// Sliding-window causal flash attention (unchanged).
// ---------------------------------------------------------------------------
__global__ __launch_bounds__(256) void attn_swa(
    const bf16* __restrict__ qkv, bf16* __restrict__ o)
{
  constexpr int PADK = 72;
  constexpr int PADV = 40;
  __shared__ bf16 Qs[64 * PADK];
  __shared__ bf16 Ks[32 * PADK];
  __shared__ bf16 Vt[64 * PADV];
  __shared__ bf16 Ps[4][16 * PADV];

  const int bid = blockIdx.x;
  const int qb = bid & 15;
  const int h  = (bid >> 4) & 15;
  const int b  = bid >> 8;
  const int q0 = qb * 64;
  const int t = threadIdx.x, lane = t & 63, w = t >> 6;
  const int l16 = lane & 15, lh = lane >> 4;

  #pragma unroll
  for (int i = 0; i < 2; i++) {
    int e = t + i * 256;
    int row = e >> 3, cc = e & 7;
    uint4 g = *(const uint4*)(qkv + ((long)(b * SMAX_ + q0 + row)) * 3072 + h * 64 + cc * 8);
    *(uint4*)(Qs + row * PADK + cc * 8) = g;
  }
  __syncthreads();
  bf16x8 aq[2];
  const int qrow = w * 16 + l16;
  #pragma unroll
  for (int ks = 0; ks < 2; ks++)
    aq[ks] = *(const bf16x8*)(Qs + qrow * PADK + ks * 32 + lh * 8);

  float m_run[4], l_run[4];
  f32x4 oacc[4];
  #pragma unroll
  for (int rr = 0; rr < 4; rr++) { m_run[rr] = -1e30f; l_run[rr] = 0.0f; }
  #pragma unroll
  for (int n = 0; n < 4; n++) oacc[n] = (f32x4){0.f, 0.f, 0.f, 0.f};

  const int tlo = q0 - (WIN_ - 1);
  const int jlo = (tlo <= 0) ? 0 : (tlo & ~31);
  const int iq  = q0 + w * 16 + lh * 4;

  for (int j0 = jlo; j0 < q0 + 64; j0 += 32) {
    __syncthreads();
    {
      int row = t >> 3, cc = t & 7;
      long base = ((long)(b * SMAX_ + j0 + row)) * 3072 + h * 64 + cc * 8;
      uint4 gk = *(const uint4*)(qkv + base + 1024);
      *(uint4*)(Ks + row * PADK + cc * 8) = gk;
      bf16x8 vv = *(const bf16x8*)(qkv + base + 2048);
      #pragma unroll
      for (int j = 0; j < 8; j++)
        Vt[(cc * 8 + j) * PADV + row] = vv[j];
    }
    __syncthreads();

    f32x4 s[2] = {(f32x4){0.f,0.f,0.f,0.f}, (f32x4){0.f,0.f,0.f,0.f}};
    #pragma unroll
    for (int nt = 0; nt < 2; nt++)
      #pragma unroll
      for (int ks = 0; ks < 2; ks++) {
        bf16x8 bk = *(const bf16x8*)(Ks + (nt * 16 + l16) * PADK + ks * 32 + lh * 8);
        s[nt] = __builtin_amdgcn_mfma_f32_16x16x32_bf16(aq[ks], bk, s[nt], 0, 0, 0);
      }

    float sc[2][4];
    #pragma unroll
    for (int nt = 0; nt < 2; nt++)
      #pragma unroll
      for (int rr = 0; rr < 4; rr++) {
        int i = iq + rr;
        int j = j0 + nt * 16 + l16;
        float v = s[nt][rr] * 0.125f;
        bool ok = (j <= i) && (i - j < WIN_);
        sc[nt][rr] = ok ? v : -1e30f;
      }

    float pb[2][4], alpha[4];
    #pragma unroll
    for (int rr = 0; rr < 4; rr++) {
      float mt = fmaxf(sc[0][rr], sc[1][rr]);
      #pragma unroll
      for (int off = 1; off < 16; off <<= 1) mt = fmaxf(mt, __shfl_xor(mt, off, 64));
      float mn = fmaxf(m_run[rr], mt);
      float a = __expf(m_run[rr] - mn);
      m_run[rr] = mn; alpha[rr] = a;
      float p0 = __expf(sc[0][rr] - mn);
      float p1 = __expf(sc[1][rr] - mn);
      pb[0][rr] = p0; pb[1][rr] = p1;
      float ls = p0 + p1;
      #pragma unroll
      for (int off = 1; off < 16; off <<= 1) ls += __shfl_xor(ls, off, 64);
      l_run[rr] = l_run[rr] * a + ls;
    }
    #pragma unroll
    for (int n = 0; n < 4; n++)
      #pragma unroll
      for (int rr = 0; rr < 4; rr++) oacc[n][rr] *= alpha[rr];

    #pragma unroll
    for (int rr = 0; rr < 4; rr++) {
      int prow = lh * 4 + rr;
      Ps[w][prow * PADV + l16]      = (bf16)pb[0][rr];
      Ps[w][prow * PADV + 16 + l16] = (bf16)pb[1][rr];
    }
    __syncthreads();

    bf16x8 pa = *(const bf16x8*)(&Ps[w][l16 * PADV + lh * 8]);
    #pragma unroll
    for (int n = 0; n < 4; n++) {
      bf16x8 bv = *(const bf16x8*)(Vt + (n * 16 + l16) * PADV + lh * 8);
      oacc[n] = __builtin_amdgcn_mfma_f32_16x16x32_bf16(pa, bv, oacc[n], 0, 0, 0);
    }
  }

  #pragma unroll
  for (int rr = 0; rr < 4; rr++) {
    int i = iq + rr;
    float inv = 1.0f / l_run[rr];
    #pragma unroll
    for (int n = 0; n < 4; n++)
      o[((long)(b * SMAX_ + i)) * D_ + h * 64 + n * 16 + l16] = (bf16)(oacc[n][rr] * inv);
  }
}

// ---------------------------------------------------------------------------
__global__ __launch_bounds__(256) void transpose_cvt(
    const float* __restrict__ src, bf16* __restrict__ dst,
    int Kk, int Nn, long srcL, long dstL)
{
  __shared__ float tile[32][33];
  const int tx = threadIdx.x, ty = threadIdx.y;
  const long n0 = (long)blockIdx.x * 32, k0 = (long)blockIdx.y * 32;
  src += (long)blockIdx.z * srcL;
  dst += (long)blockIdx.z * dstL;
  #pragma unroll
  for (int i = 0; i < 4; i++)
    tile[ty + i * 8][tx] = src[(k0 + ty + i * 8) * Nn + n0 + tx];
  __syncthreads();
  #pragma unroll
  for (int i = 0; i < 4; i++)
    dst[(n0 + ty + i * 8) * Kk + k0 + tx] = (bf16)tile[tx][ty + i * 8];
}

__global__ __launch_bounds__(256) void cvt_bf16(
    const float* __restrict__ src, bf16* __restrict__ dst, long n4)
{
  long i = (long)blockIdx.x * 256 + threadIdx.x;
  if (i >= n4) return;
  float4 v = ((const float4*)src)[i];
  bf16x4 o; o[0] = (bf16)v.x; o[1] = (bf16)v.y; o[2] = (bf16)v.z; o[3] = (bf16)v.w;
  ((bf16x4*)dst)[i] = o;
}

__global__ __launch_bounds__(256) void pack_bqkv(
    const float* __restrict__ bq, const float* __restrict__ bk,
    const float* __restrict__ bv, float* __restrict__ out)
{
  int i = blockIdx.x * 256 + threadIdx.x;
  if (i >= L_ * 3072) return;
  int l = i / 3072, c = i % 3072;
  float v = (c < 1024) ? bq[l * 1024 + c]
          : (c < 2048) ? bk[l * 1024 + c - 1024]
                       : bv[l * 1024 + c - 2048];
  out[i] = v;
}

__global__ __launch_bounds__(256) void embed_k(
    const int* __restrict__ ids, const float* __restrict__ emb,
    const float* __restrict__ pos, float* __restrict__ x)
{
  const int m = blockIdx.x, t = threadIdx.x;
  const int id = ids[m];
  const int s = m & (SMAX_ - 1);
  float4 e = ((const float4*)(emb + (long)id * D_))[t];
  float4 p = ((const float4*)(pos + (long)s * D_))[t];
  float4 rr; rr.x = e.x + p.x; rr.y = e.y + p.y; rr.z = e.z + p.z; rr.w = e.w + p.w;
  ((float4*)(x + (long)m * D_))[t] = rr;
}

__global__ __launch_bounds__(256) void rmsnorm_k(
    const float* __restrict__ x, const float* __restrict__ wgt,
    bf16* __restrict__ out)
{
  __shared__ float red[4];
  const int m = blockIdx.x, t = threadIdx.x;
  float4 v = ((const float4*)(x + (long)m * D_))[t];
  float ss = v.x * v.x + v.y * v.y + v.z * v.z + v.w * v.w;
  #pragma unroll
  for (int off = 1; off < 64; off <<= 1) ss += __shfl_xor(ss, off, 64);
  const int lane = t & 63, w = t >> 6;
  if (lane == 0) red[w] = ss;
  __syncthreads();
  float tot = red[0] + red[1] + red[2] + red[3];
  float rs = rsqrtf(tot * (1.0f / D_) + 1e-6f);
  float4 g = ((const float4*)wgt)[t];
  bf16x4 o;
  o[0] = (bf16)(v.x * rs * g.x); o[1] = (bf16)(v.y * rs * g.y);
  o[2] = (bf16)(v.z * rs * g.z); o[3] = (bf16)(v.w * rs * g.w);
  ((bf16x4*)(out + (long)m * D_))[t] = o;
}

// ---------------------------------------------------------------------------
extern "C" void kernel_launch(void* const* d_in, const int* in_sizes, int n_in,
                              void* d_out, int out_size, void* d_ws, size_t ws_size,
                              hipStream_t stream)
{
  const int*   ids = (const int*)d_in[0];
  const float* emb = (const float*)d_in[1];
  const float* pos = (const float*)d_in[2];
  const float* n1w = (const float*)d_in[3];
  const float* n2w = (const float*)d_in[4];
  const float* wq  = (const float*)d_in[5];
  const float* bq  = (const float*)d_in[6];
  const float* wk  = (const float*)d_in[7];
  const float* bk  = (const float*)d_in[8];
  const float* wv  = (const float*)d_in[9];
  const float* bv  = (const float*)d_in[10];
  const float* wo  = (const float*)d_in[11];
  const float* bo  = (const float*)d_in[12];
  const float* w1  = (const float*)d_in[13];
  const float* b1  = (const float*)d_in[14];
  const float* w2  = (const float*)d_in[15];
  const float* b2  = (const float*)d_in[16];
  const float* nfw = (const float*)d_in[17];

  char* p = (char*)d_ws;
  auto alloc = [&](size_t bytes) {
    char* rr = p; p += (bytes + 255) & ~(size_t)255; return rr;
  };
  bf16*  wqkv_t = (bf16*) alloc((size_t)L_ * 3 * 1024 * 1024 * 2);
  bf16*  wo_t   = (bf16*) alloc((size_t)L_ * 1024 * 1024 * 2);
  bf16*  w1_t   = (bf16*) alloc((size_t)L_ * 4096 * 1024 * 2);
  bf16*  w2_t   = (bf16*) alloc((size_t)L_ * 1024 * 4096 * 2);
  bf16*  emb_bf = (bf16*) alloc((size_t)V_ * D_ * 2);
  float* bqkv   = (float*)alloc((size_t)L_ * 3072 * 4);
  float* x      = (float*)alloc((size_t)M_ * D_ * 4);
  bf16*  hbuf   = (bf16*) alloc((size_t)M_ * D_ * 2);
  bf16*  qkv    = (bf16*) alloc((size_t)M_ * 3072 * 2);
  bf16*  obuf   = (bf16*) alloc((size_t)M_ * D_ * 2);
  bf16*  ff     = (bf16*) alloc((size_t)M_ * DFF_ * 2);

  const dim3 b32(32, 8, 1);
  transpose_cvt<<<dim3(32, 32, L_),  b32, 0, stream>>>(wq, wqkv_t,                1024, 1024, 1024 * 1024, 3 * 1024 * 1024);
  transpose_cvt<<<dim3(32, 32, L_),  b32, 0, stream>>>(wk, wqkv_t + 1024 * 1024,  1024, 1024, 1024 * 1024, 3 * 1024 * 1024);
  transpose_cvt<<<dim3(32, 32, L_),  b32, 0, stream>>>(wv, wqkv_t + 2*1024*1024,  1024, 1024, 1024 * 1024, 3 * 1024 * 1024);
  transpose_cvt<<<dim3(32, 32, L_),  b32, 0, stream>>>(wo, wo_t,                  1024, 1024, 1024 * 1024, 1024 * 1024);
  transpose_cvt<<<dim3(128, 32, L_), b32, 0, stream>>>(w1, w1_t,                  1024, 4096, 1024 * 4096, 4096 * 1024);
  transpose_cvt<<<dim3(32, 128, L_), b32, 0, stream>>>(w2, w2_t,                  4096, 1024, 4096 * 1024, 1024 * 4096);
  cvt_bf16<<<32000, 256, 0, stream>>>(emb, emb_bf, (long)V_ * D_ / 4);
  pack_bqkv<<<24, 256, 0, stream>>>(bq, bk, bv, bqkv);
  embed_k<<<M_, 256, 0, stream>>>(ids, emb, pos, x);

  for (int l = 0; l < L_; l++) {
    rmsnorm_k<<<M_, 256, 0, stream>>>(x, n1w + l * D_, hbuf);
    gemm_bt<128, 0><<<dim3(16 * 24), 256, 0, stream>>>(
        hbuf, wqkv_t + (size_t)l * 3 * 1024 * 1024, bqkv + l * 3072,
        nullptr, qkv, nullptr, 3072, 1024, 15, 4);
    attn_swa<<<B_ * H_ * (SMAX_ / 64), 256, 0, stream>>>(qkv, obuf);
    gemm_bt<64, 2><<<dim3(32 * 8), 256, 0, stream>>>(
        obuf, wo_t + (size_t)l * 1024 * 1024, bo + l * D_,
        x, nullptr, nullptr, 1024, 1024, 31, 5);
    rmsnorm_k<<<M_, 256, 0, stream>>>(x, n2w + l * D_, hbuf);
    gemm_bt<128, 1><<<dim3(16 * 32), 256, 0, stream>>>(
        hbuf, w1_t + (size_t)l * 4096 * 1024, b1 + l * DFF_,
        nullptr, ff, nullptr, 4096, 1024, 15, 4);
    gemm_bt<64, 2><<<dim3(32 * 8), 256, 0, stream>>>(
        ff, w2_t + (size_t)l * 1024 * 4096, b2 + l * D_,
        x, nullptr, nullptr, 1024, 4096, 31, 5);
  }
  rmsnorm_k<<<M_, 256, 0, stream>>>(x, nfw, hbuf);
  gemm256_lm<<<dim3(8 * (V_ / 256)), 512, 0, stream>>>(
      hbuf, emb_bf, (float*)d_out, V_);
}

// Round 4
// 628.359 us; speedup vs baseline: 1.3100x; 1.1505x over previous
//
#include <hip/hip_runtime.h>
#include <hip/hip_bf16.h>
#include <cstdint>

typedef __bf16 bf16;
typedef __bf16 bf16x8 __attribute__((ext_vector_type(8)));
typedef __bf16 bf16x4 __attribute__((ext_vector_type(4)));
typedef float  f32x4  __attribute__((ext_vector_type(4)));

constexpr int V_    = 32000;
constexpr int SMAX_ = 1024;
constexpr int D_    = 1024;
constexpr int H_    = 16;
constexpr int L_    = 2;
constexpr int DFF_  = 4096;
constexpr int WIN_  = 256;
constexpr int B_    = 2;
constexpr int M_    = B_ * SMAX_; // 2048

#define SBAR0_() __builtin_amdgcn_sched_barrier(0)
#define HWBAR_() { __builtin_amdgcn_s_barrier(); SBAR0_(); }
#define LGKM0_() { asm volatile("s_waitcnt lgkmcnt(0)" ::: "memory"); SBAR0_(); }

// ---------------------------------------------------------------------------
// LM head: 256x256 tile, depth-3 BK=32 pipeline, 4 LDS buffers, 8 waves.
// out[M,Nn](f32) = A[M,1024] @ BT[Nn,1024]^T.
// Per sub-tile: vmcnt(8)+bar -> 12 ds_read -> stage(+3) -> lgkm0 -> 32 MFMA.
// ---------------------------------------------------------------------------
__global__ __launch_bounds__(512, 1) void gemm256_deep(
    const bf16* __restrict__ A, const bf16* __restrict__ BT,
    float* __restrict__ outf, int Nn)
{
  constexpr int KK = 1024, NT = KK / 32;
  __shared__ __align__(16) bf16 ldsA[4 * 8192];   // 4 bufs x 256 rows x 32
  __shared__ __align__(16) bf16 ldsB[4 * 8192];

  const int t = threadIdx.x, lane = t & 63, w = t >> 6;
  const int l16 = lane & 15, lh = lane >> 4;
  const int wm = w >> 2, wn = w & 3;

  const int nloc = gridDim.x >> 3;
  const int wg = (blockIdx.x & 7) * nloc + (blockIdx.x >> 3);
  const long m0 = (long)(wg & 7) * 256;
  const long n0 = (long)(wg >> 3) * 256;

  // stage one 256x32 sub-tile (16KB) into region dst; linear dest, inverse-
  // swizzled source (slot ^= row&3). 2 calls x 512 thr x 16B.
  auto STG = [&](const bf16* src, long rowBase, bf16* dst, int k0) {
    #pragma unroll
    for (int j = 0; j < 2; ++j) {
      int p = j * 8192 + t * 16;           // phys byte in region
      int row = p >> 6;
      int sl = ((p >> 4) & 3) ^ (row & 3);
      const bf16* g = src + (rowBase + row) * (long)KK + k0 + sl * 8;
      __builtin_amdgcn_global_load_lds(
          (const __attribute__((address_space(1))) uint32_t*)g,
          (__attribute__((address_space(3))) uint32_t*)(dst + j * 4096 + w * 512),
          16, 0, 0);
    }
  };
  auto LDF = [&](const bf16* base, int rowb) -> bf16x8 {
    int row = rowb + l16;                  // rowb multiple of 16 -> row&3==l16&3
    return *(const bf16x8*)(base + row * 32 + ((lh ^ (l16 & 3)) << 3));
  };

  f32x4 acc[8][4] = {};

  STG(A, m0, ldsA,          0);  STG(BT, n0, ldsB,          0);
  STG(A, m0, ldsA + 8192,  32);  STG(BT, n0, ldsB + 8192,  32);
  STG(A, m0, ldsA + 16384, 64);  STG(BT, n0, ldsB + 16384, 64);
  int kNext = 96;

  for (int i = 0; i < NT; ++i) {
    const int cur = i & 3, nb = (i + 3) & 3;
    asm volatile("s_waitcnt vmcnt(8)" ::: "memory"); SBAR0_();
    HWBAR_();
    const bf16* Ac = ldsA + cur * 8192;
    const bf16* Bc = ldsB + cur * 8192;
    bf16x8 af[8], bb[4];
    #pragma unroll
    for (int mi = 0; mi < 8; ++mi) af[mi] = LDF(Ac, wm * 128 + mi * 16);
    #pragma unroll
    for (int ni = 0; ni < 4; ++ni) bb[ni] = LDF(Bc, wn * 64 + ni * 16);
    STG(A, m0, ldsA + nb * 8192, kNext);
    STG(BT, n0, ldsB + nb * 8192, kNext);
    kNext += 32; if (kNext == KK) kNext = 0;
    LGKM0_();
    __builtin_amdgcn_s_setprio(1);
    #pragma unroll
    for (int mi = 0; mi < 8; ++mi)
      #pragma unroll
      for (int ni = 0; ni < 4; ++ni)
        acc[mi][ni] = __builtin_amdgcn_mfma_f32_16x16x32_bf16(af[mi], bb[ni], acc[mi][ni], 0, 0, 0);
    __builtin_amdgcn_s_setprio(0);
  }

  #pragma unroll
  for (int mi = 0; mi < 8; ++mi)
    #pragma unroll
    for (int ni = 0; ni < 4; ++ni)
      #pragma unroll
      for (int rr = 0; rr < 4; ++rr) {
        long row = m0 + wm * 128 + mi * 16 + lh * 4 + rr;
        long col = n0 + wn * 64 + ni * 16 + l16;
        outf[row * Nn + col] = acc[mi][ni][rr];
      }
}

// ---------------------------------------------------------------------------
// Layer GEMMs: BM x 128 tile, same depth-3 BK=32 pipeline, 4 waves (2x2).
// BM=128: LPS=4 (vmcnt 8), 64KB LDS, 2 blk/CU. BM=64: LPS=3 (vmcnt 6), 48KB.
// EPI: 0 bias->bf16, 1 bias+gelu->bf16, 2 bias+residual->f32, 3 ->f32
// ---------------------------------------------------------------------------
template<int BM, int EPI>
__global__ __launch_bounds__(256, (BM == 128 ? 2 : 3)) void gemm_deep(
    const bf16* __restrict__ A, const bf16* __restrict__ BT,
    const float* __restrict__ bias, float* __restrict__ resid,
    bf16* __restrict__ outb, float* __restrict__ outf,
    int Nn, int Kk, int nbyMask, int nbyShift)
{
  constexpr int WR = BM / 32;        // A fragments per wave
  constexpr int CA = BM / 64;        // A stage calls (2 or 1)
  constexpr int LPS = CA + 2;        // loads per sub-tile per wave
  __shared__ __align__(16) bf16 ldsA[4 * BM * 32];
  __shared__ __align__(16) bf16 ldsB[4 * 4096];

  const int t = threadIdx.x, lane = t & 63, w = t >> 6;
  const int l16 = lane & 15, lh = lane >> 4;
  const int wm = w >> 1, wn = w & 1;

  const int nwg = gridDim.x, bid = blockIdx.x;
  const int nloc = nwg >> 3;
  const int wg = (bid & 7) * nloc + (bid >> 3);
  const long m0 = (long)(wg & nbyMask) * BM;
  const long n0 = (long)(wg >> nbyShift) * 128;

  auto STGA = [&](bf16* dst, int k0) {
    #pragma unroll
    for (int j = 0; j < CA; ++j) {
      int p = j * 4096 + t * 16;
      int row = p >> 6;
      int sl = ((p >> 4) & 3) ^ (row & 3);
      const bf16* g = A + (m0 + row) * (long)Kk + k0 + sl * 8;
      __builtin_amdgcn_global_load_lds(
          (const __attribute__((address_space(1))) uint32_t*)g,
          (__attribute__((address_space(3))) uint32_t*)(dst + j * 2048 + w * 512),
          16, 0, 0);
    }
  };
  auto STGB = [&](bf16* dst, int k0) {
    #pragma unroll
    for (int j = 0; j < 2; ++j) {
      int p = j * 4096 + t * 16;
      int row = p >> 6;
      int sl = ((p >> 4) & 3) ^ (row & 3);
      const bf16* g = BT + (n0 + row) * (long)Kk + k0 + sl * 8;
      __builtin_amdgcn_global_load_lds(
          (const __attribute__((address_space(1))) uint32_t*)g,
          (__attribute__((address_space(3))) uint32_t*)(dst + j * 2048 + w * 512),
          16, 0, 0);
    }
  };
  auto LDF = [&](const bf16* base, int rowb) -> bf16x8 {
    int row = rowb + l16;
    return *(const bf16x8*)(base + row * 32 + ((lh ^ (l16 & 3)) << 3));
  };

  f32x4 acc[WR][4] = {};

  STGA(ldsA,               0);  STGB(ldsB,        0);
  STGA(ldsA + BM * 32,    32);  STGB(ldsB + 4096, 32);
  STGA(ldsA + 2 * BM * 32, 64); STGB(ldsB + 8192, 64);
  int kNext = 96;

  const int NT = Kk >> 5;
  for (int i = 0; i < NT; ++i) {
    const int cur = i & 3, nb = (i + 3) & 3;
    if constexpr (LPS == 4) { asm volatile("s_waitcnt vmcnt(8)" ::: "memory"); }
    else                    { asm volatile("s_waitcnt vmcnt(6)" ::: "memory"); }
    SBAR0_();
    HWBAR_();
    const bf16* Ac = ldsA + cur * BM * 32;
    const bf16* Bc = ldsB + cur * 4096;
    bf16x8 af[WR], bb[4];
    #pragma unroll
    for (int mi = 0; mi < WR; ++mi) af[mi] = LDF(Ac, wm * (WR * 16) + mi * 16);
    #pragma unroll
    for (int ni = 0; ni < 4; ++ni) bb[ni] = LDF(Bc, wn * 64 + ni * 16);
    STGA(ldsA + nb * BM * 32, kNext);
    STGB(ldsB + nb * 4096, kNext);
    kNext += 32; if (kNext == Kk) kNext = 0;
    LGKM0_();
    __builtin_amdgcn_s_setprio(1);
    #pragma unroll
    for (int mi = 0; mi < WR; ++mi)
      #pragma unroll
      for (int ni = 0; ni < 4; ++ni)
        acc[mi][ni] = __builtin_amdgcn_mfma_f32_16x16x32_bf16(af[mi], bb[ni], acc[mi][ni], 0, 0, 0);
    __builtin_amdgcn_s_setprio(0);
  }

  #pragma unroll
  for (int mi = 0; mi < WR; ++mi)
    #pragma unroll
    for (int ni = 0; ni < 4; ++ni)
      #pragma unroll
      for (int rr = 0; rr < 4; ++rr) {
        long row = m0 + wm * (WR * 16) + mi * 16 + lh * 4 + rr;
        long col = n0 + wn * 64 + ni * 16 + l16;
        float v = acc[mi][ni][rr];
        if (EPI == 0) {
          outb[row * Nn + col] = (bf16)(v + bias[col]);
        } else if (EPI == 1) {
          float xx = v + bias[col];
          outb[row * Nn + col] = (bf16)(0.5f * xx * (1.0f + erff(xx * 0.70710678118654752f)));
        } else if (EPI == 2) {
          resid[row * Nn + col] += v + bias[col];
        } else {
          outf[row * Nn + col] = v;
        }
      }
}

// ---------------------------------------------------------------------------
// Sliding-window causal flash attention (unchanged).
// ---------------------------------------------------------------------------
__global__ __launch_bounds__(256) void attn_swa(
    const bf16* __restrict__ qkv, bf16* __restrict__ o)
{
  constexpr int PADK = 72;
  constexpr int PADV = 40;
  __shared__ bf16 Qs[64 * PADK];
  __shared__ bf16 Ks[32 * PADK];
  __shared__ bf16 Vt[64 * PADV];
  __shared__ bf16 Ps[4][16 * PADV];

  const int bid = blockIdx.x;
  const int qb = bid & 15;
  const int h  = (bid >> 4) & 15;
  const int b  = bid >> 8;
  const int q0 = qb * 64;
  const int t = threadIdx.x, lane = t & 63, w = t >> 6;
  const int l16 = lane & 15, lh = lane >> 4;

  #pragma unroll
  for (int i = 0; i < 2; i++) {
    int e = t + i * 256;
    int row = e >> 3, cc = e & 7;
    uint4 g = *(const uint4*)(qkv + ((long)(b * SMAX_ + q0 + row)) * 3072 + h * 64 + cc * 8);
    *(uint4*)(Qs + row * PADK + cc * 8) = g;
  }
  __syncthreads();
  bf16x8 aq[2];
  const int qrow = w * 16 + l16;
  #pragma unroll
  for (int ks = 0; ks < 2; ks++)
    aq[ks] = *(const bf16x8*)(Qs + qrow * PADK + ks * 32 + lh * 8);

  float m_run[4], l_run[4];
  f32x4 oacc[4];
  #pragma unroll
  for (int rr = 0; rr < 4; rr++) { m_run[rr] = -1e30f; l_run[rr] = 0.0f; }
  #pragma unroll
  for (int n = 0; n < 4; n++) oacc[n] = (f32x4){0.f, 0.f, 0.f, 0.f};

  const int tlo = q0 - (WIN_ - 1);
  const int jlo = (tlo <= 0) ? 0 : (tlo & ~31);
  const int iq  = q0 + w * 16 + lh * 4;

  for (int j0 = jlo; j0 < q0 + 64; j0 += 32) {
    __syncthreads();
    {
      int row = t >> 3, cc = t & 7;
      long base = ((long)(b * SMAX_ + j0 + row)) * 3072 + h * 64 + cc * 8;
      uint4 gk = *(const uint4*)(qkv + base + 1024);
      *(uint4*)(Ks + row * PADK + cc * 8) = gk;
      bf16x8 vv = *(const bf16x8*)(qkv + base + 2048);
      #pragma unroll
      for (int j = 0; j < 8; j++)
        Vt[(cc * 8 + j) * PADV + row] = vv[j];
    }
    __syncthreads();

    f32x4 s[2] = {(f32x4){0.f,0.f,0.f,0.f}, (f32x4){0.f,0.f,0.f,0.f}};
    #pragma unroll
    for (int nt = 0; nt < 2; nt++)
      #pragma unroll
      for (int ks = 0; ks < 2; ks++) {
        bf16x8 bk = *(const bf16x8*)(Ks + (nt * 16 + l16) * PADK + ks * 32 + lh * 8);
        s[nt] = __builtin_amdgcn_mfma_f32_16x16x32_bf16(aq[ks], bk, s[nt], 0, 0, 0);
      }

    float sc[2][4];
    #pragma unroll
    for (int nt = 0; nt < 2; nt++)
      #pragma unroll
      for (int rr = 0; rr < 4; rr++) {
        int i = iq + rr;
        int j = j0 + nt * 16 + l16;
        float v = s[nt][rr] * 0.125f;
        bool ok = (j <= i) && (i - j < WIN_);
        sc[nt][rr] = ok ? v : -1e30f;
      }

    float pb[2][4], alpha[4];
    #pragma unroll
    for (int rr = 0; rr < 4; rr++) {
      float mt = fmaxf(sc[0][rr], sc[1][rr]);
      #pragma unroll
      for (int off = 1; off < 16; off <<= 1) mt = fmaxf(mt, __shfl_xor(mt, off, 64));
      float mn = fmaxf(m_run[rr], mt);
      float a = __expf(m_run[rr] - mn);
      m_run[rr] = mn; alpha[rr] = a;
      float p0 = __expf(sc[0][rr] - mn);
      float p1 = __expf(sc[1][rr] - mn);
      pb[0][rr] = p0; pb[1][rr] = p1;
      float ls = p0 + p1;
      #pragma unroll
      for (int off = 1; off < 16; off <<= 1) ls += __shfl_xor(ls, off, 64);
      l_run[rr] = l_run[rr] * a + ls;
    }
    #pragma unroll
    for (int n = 0; n < 4; n++)
      #pragma unroll
      for (int rr = 0; rr < 4; rr++) oacc[n][rr] *= alpha[rr];

    #pragma unroll
    for (int rr = 0; rr < 4; rr++) {
      int prow = lh * 4 + rr;
      Ps[w][prow * PADV + l16]      = (bf16)pb[0][rr];
      Ps[w][prow * PADV + 16 + l16] = (bf16)pb[1][rr];
    }
    __syncthreads();

    bf16x8 pa = *(const bf16x8*)(&Ps[w][l16 * PADV + lh * 8]);
    #pragma unroll
    for (int n = 0; n < 4; n++) {
      bf16x8 bv = *(const bf16x8*)(Vt + (n * 16 + l16) * PADV + lh * 8);
      oacc[n] = __builtin_amdgcn_mfma_f32_16x16x32_bf16(pa, bv, oacc[n], 0, 0, 0);
    }
  }

  #pragma unroll
  for (int rr = 0; rr < 4; rr++) {
    int i = iq + rr;
    float inv = 1.0f / l_run[rr];
    #pragma unroll
    for (int n = 0; n < 4; n++)
      o[((long)(b * SMAX_ + i)) * D_ + h * 64 + n * 16 + l16] = (bf16)(oacc[n][rr] * inv);
  }
}

// ---------------------------------------------------------------------------
__global__ __launch_bounds__(256) void transpose_cvt(
    const float* __restrict__ src, bf16* __restrict__ dst,
    int Kk, int Nn, long srcL, long dstL)
{
  __shared__ float tile[32][33];
  const int tx = threadIdx.x, ty = threadIdx.y;
  const long n0 = (long)blockIdx.x * 32, k0 = (long)blockIdx.y * 32;
  src += (long)blockIdx.z * srcL;
  dst += (long)blockIdx.z * dstL;
  #pragma unroll
  for (int i = 0; i < 4; i++)
    tile[ty + i * 8][tx] = src[(k0 + ty + i * 8) * Nn + n0 + tx];
  __syncthreads();
  #pragma unroll
  for (int i = 0; i < 4; i++)
    dst[(n0 + ty + i * 8) * Kk + k0 + tx] = (bf16)tile[tx][ty + i * 8];
}

__global__ __launch_bounds__(256) void cvt_bf16(
    const float* __restrict__ src, bf16* __restrict__ dst, long n4)
{
  long i = (long)blockIdx.x * 256 + threadIdx.x;
  if (i >= n4) return;
  float4 v = ((const float4*)src)[i];
  bf16x4 o; o[0] = (bf16)v.x; o[1] = (bf16)v.y; o[2] = (bf16)v.z; o[3] = (bf16)v.w;
  ((bf16x4*)dst)[i] = o;
}

__global__ __launch_bounds__(256) void pack_bqkv(
    const float* __restrict__ bq, const float* __restrict__ bk,
    const float* __restrict__ bv, float* __restrict__ out)
{
  int i = blockIdx.x * 256 + threadIdx.x;
  if (i >= L_ * 3072) return;
  int l = i / 3072, c = i % 3072;
  float v = (c < 1024) ? bq[l * 1024 + c]
          : (c < 2048) ? bk[l * 1024 + c - 1024]
                       : bv[l * 1024 + c - 2048];
  out[i] = v;
}

__global__ __launch_bounds__(256) void embed_k(
    const int* __restrict__ ids, const float* __restrict__ emb,
    const float* __restrict__ pos, float* __restrict__ x)
{
  const int m = blockIdx.x, t = threadIdx.x;
  const int id = ids[m];
  const int s = m & (SMAX_ - 1);
  float4 e = ((const float4*)(emb + (long)id * D_))[t];
  float4 p = ((const float4*)(pos + (long)s * D_))[t];
  float4 rr; rr.x = e.x + p.x; rr.y = e.y + p.y; rr.z = e.z + p.z; rr.w = e.w + p.w;
  ((float4*)(x + (long)m * D_))[t] = rr;
}

__global__ __launch_bounds__(256) void rmsnorm_k(
    const float* __restrict__ x, const float* __restrict__ wgt,
    bf16* __restrict__ out)
{
  __shared__ float red[4];
  const int m = blockIdx.x, t = threadIdx.x;
  float4 v = ((const float4*)(x + (long)m * D_))[t];
  float ss = v.x * v.x + v.y * v.y + v.z * v.z + v.w * v.w;
  #pragma unroll
  for (int off = 1; off < 64; off <<= 1) ss += __shfl_xor(ss, off, 64);
  const int lane = t & 63, w = t >> 6;
  if (lane == 0) red[w] = ss;
  __syncthreads();
  float tot = red[0] + red[1] + red[2] + red[3];
  float rs = rsqrtf(tot * (1.0f / D_) + 1e-6f);
  float4 g = ((const float4*)wgt)[t];
  bf16x4 o;
  o[0] = (bf16)(v.x * rs * g.x); o[1] = (bf16)(v.y * rs * g.y);
  o[2] = (bf16)(v.z * rs * g.z); o[3] = (bf16)(v.w * rs * g.w);
  ((bf16x4*)(out + (long)m * D_))[t] = o;
}

// ---------------------------------------------------------------------------
extern "C" void kernel_launch(void* const* d_in, const int* in_sizes, int n_in,
                              void* d_out, int out_size, void* d_ws, size_t ws_size,
                              hipStream_t stream)
{
  const int*   ids = (const int*)d_in[0];
  const float* emb = (const float*)d_in[1];
  const float* pos = (const float*)d_in[2];
  const float* n1w = (const float*)d_in[3];
  const float* n2w = (const float*)d_in[4];
  const float* wq  = (const float*)d_in[5];
  const float* bq  = (const float*)d_in[6];
  const float* wk  = (const float*)d_in[7];
  const float* bk  = (const float*)d_in[8];
  const float* wv  = (const float*)d_in[9];
  const float* bv  = (const float*)d_in[10];
  const float* wo  = (const float*)d_in[11];
  const float* bo  = (const float*)d_in[12];
  const float* w1  = (const float*)d_in[13];
  const float* b1  = (const float*)d_in[14];
  const float* w2  = (const float*)d_in[15];
  const float* b2  = (const float*)d_in[16];
  const float* nfw = (const float*)d_in[17];

  char* p = (char*)d_ws;
  auto alloc = [&](size_t bytes) {
    char* rr = p; p += (bytes + 255) & ~(size_t)255; return rr;
  };
  bf16*  wqkv_t = (bf16*) alloc((size_t)L_ * 3 * 1024 * 1024 * 2);
  bf16*  wo_t   = (bf16*) alloc((size_t)L_ * 1024 * 1024 * 2);
  bf16*  w1_t   = (bf16*) alloc((size_t)L_ * 4096 * 1024 * 2);
  bf16*  w2_t   = (bf16*) alloc((size_t)L_ * 1024 * 4096 * 2);
  bf16*  emb_bf = (bf16*) alloc((size_t)V_ * D_ * 2);
  float* bqkv   = (float*)alloc((size_t)L_ * 3072 * 4);
  float* x      = (float*)alloc((size_t)M_ * D_ * 4);
  bf16*  hbuf   = (bf16*) alloc((size_t)M_ * D_ * 2);
  bf16*  qkv    = (bf16*) alloc((size_t)M_ * 3072 * 2);
  bf16*  obuf   = (bf16*) alloc((size_t)M_ * D_ * 2);
  bf16*  ff     = (bf16*) alloc((size_t)M_ * DFF_ * 2);

  const dim3 b32(32, 8, 1);
  transpose_cvt<<<dim3(32, 32, L_),  b32, 0, stream>>>(wq, wqkv_t,                1024, 1024, 1024 * 1024, 3 * 1024 * 1024);
  transpose_cvt<<<dim3(32, 32, L_),  b32, 0, stream>>>(wk, wqkv_t + 1024 * 1024,  1024, 1024, 1024 * 1024, 3 * 1024 * 1024);
  transpose_cvt<<<dim3(32, 32, L_),  b32, 0, stream>>>(wv, wqkv_t + 2*1024*1024,  1024, 1024, 1024 * 1024, 3 * 1024 * 1024);
  transpose_cvt<<<dim3(32, 32, L_),  b32, 0, stream>>>(wo, wo_t,                  1024, 1024, 1024 * 1024, 1024 * 1024);
  transpose_cvt<<<dim3(128, 32, L_), b32, 0, stream>>>(w1, w1_t,                  1024, 4096, 1024 * 4096, 4096 * 1024);
  transpose_cvt<<<dim3(32, 128, L_), b32, 0, stream>>>(w2, w2_t,                  4096, 1024, 4096 * 1024, 1024 * 4096);
  cvt_bf16<<<32000, 256, 0, stream>>>(emb, emb_bf, (long)V_ * D_ / 4);
  pack_bqkv<<<24, 256, 0, stream>>>(bq, bk, bv, bqkv);
  embed_k<<<M_, 256, 0, stream>>>(ids, emb, pos, x);

  for (int l = 0; l < L_; l++) {
    rmsnorm_k<<<M_, 256, 0, stream>>>(x, n1w + l * D_, hbuf);
    gemm_deep<128, 0><<<dim3(16 * 24), 256, 0, stream>>>(
        hbuf, wqkv_t + (size_t)l * 3 * 1024 * 1024, bqkv + l * 3072,
        nullptr, qkv, nullptr, 3072, 1024, 15, 4);
    attn_swa<<<B_ * H_ * (SMAX_ / 64), 256, 0, stream>>>(qkv, obuf);
    gemm_deep<64, 2><<<dim3(32 * 8), 256, 0, stream>>>(
        obuf, wo_t + (size_t)l * 1024 * 1024, bo + l * D_,
        x, nullptr, nullptr, 1024, 1024, 31, 5);
    rmsnorm_k<<<M_, 256, 0, stream>>>(x, n2w + l * D_, hbuf);
    gemm_deep<128, 1><<<dim3(16 * 32), 256, 0, stream>>>(
        hbuf, w1_t + (size_t)l * 4096 * 1024, b1 + l * DFF_,
        nullptr, ff, nullptr, 4096, 1024, 15, 4);
    gemm_deep<64, 2><<<dim3(32 * 8), 256, 0, stream>>>(
        ff, w2_t + (size_t)l * 1024 * 4096, b2 + l * D_,
        x, nullptr, nullptr, 1024, 4096, 31, 5);
  }
  rmsnorm_k<<<M_, 256, 0, stream>>>(x, nfw, hbuf);
  gemm256_deep<<<dim3(8 * (V_ / 256)), 512, 0, stream>>>(
      hbuf, emb_bf, (float*)d_out, V_);
}